// Round 4
// baseline (170.154 us; speedup 1.0000x reference)
//
#include <hip/hip_runtime.h>
#include <math.h>

#define HH 64
#define WW 64
#define NB 4
#define NV ((HH-1)*WW)      // 4032 vertical candidates
#define NHZ (HH*(WW-1))     // 4032 horizontal candidates
#define NP (NV+NHZ)         // 8064 candidates per image
#define EPSF 1e-3f
#define BANDF 3.0f
#define BIGF 1e10f
#define SENTV 1e5f          // sentinel coord; d2 ~ 2e10 > BIGF, never selected
#define NGCAP 5088          // LDS G capacity (mult of 32); 40704 B -> 4 blocks/CU
#define PPB 32              // P points per k_nn block
#define NBLK_P ((NP+PPB-1)/PPB)   // 252
#define GRID_NN (NB*NBLK_P)       // 1008

// ---- ws layout ----
// float2 Pp[NB][NP], float2 Gp[NB][NP]
// int NPv[NB], NGv[NB]
// float acc[12] : S[4], l1n[4], l1[4]
// int ctr

__device__ __forceinline__ bool cand_point(const float* __restrict__ s, int p,
                                           float& pr, float& pc) {
  float v1, v2; int i, j; bool vert = (p < NV);
  if (vert) {
    i = p >> 6; j = p & 63;
    v1 = s[i*WW + j]; v2 = s[(i+1)*WW + j];
  } else {
    int q = p - NV; i = q / (WW-1); j = q - i*(WW-1);
    v1 = s[i*WW + j]; v2 = s[i*WW + j + 1];
  }
  float a1 = fabsf(v1), a2 = fabsf(v2);
  // sign(v1)*sign(v2)<0 == v1*v2<0 when neither |v|<=EPS (no underflow then)
  bool valid = (v1*v2 < 0.0f) || (a1 <= EPSF) || (a2 <= EPSF);
  float a = a1 / fmaxf(a1 + a2, 1e-8f);
  a = fminf(fmaxf(a, 0.0f), 1.0f);
  pr = vert ? ((float)i + a) : (float)i;
  pc = vert ? (float)j       : ((float)j + a);
  return valid;
}

__device__ __forceinline__ void normal_at(const float* __restrict__ s, int r, int c,
                                          float& nr, float& nc) {
  float grm = (r == 0)    ? (s[WW + c] - s[c])
            : (r == HH-1) ? (s[(HH-1)*WW + c] - s[(HH-2)*WW + c])
                          : 0.5f * (s[(r+1)*WW + c] - s[(r-1)*WW + c]);
  float gcm = (c == 0)    ? (s[r*WW + 1] - s[r*WW])
            : (c == WW-1) ? (s[r*WW + WW-1] - s[r*WW + WW-2])
                          : 0.5f * (s[r*WW + c + 1] - s[r*WW + c - 1]);
  nr = grm; nc = gcm;
}

// K1: 8 blocks. blk>>2==0: compact gt->Gp (+ zero acc/ctr); ==1: compact
// pred->Pp + per-batch L1 sum. Pass 1 caches (r,c)+ballot masks in LDS so
// pass 2 is pure LDS->global.
__global__ __launch_bounds__(256) void k_prep(const float* __restrict__ pred,
                                              const float* __restrict__ gt,
                                              float2* __restrict__ Pp,
                                              float2* __restrict__ Gp,
                                              int* __restrict__ NPv,
                                              int* __restrict__ NGv,
                                              float* __restrict__ acc,
                                              int* __restrict__ ctr) {
  int which = blockIdx.x >> 2;     // 0: gt, 1: pred
  int b = blockIdx.x & 3;
  const float* src = which ? (pred + b*HH*WW) : (gt + b*HH*WW);
  float2* dst = which ? (Pp + (size_t)b*NP) : (Gp + (size_t)b*NP);
  int* cnt_out = which ? NPv : NGv;

  __shared__ float2 cval[NP];                  // 64512 B
  __shared__ unsigned long long cmask[4*32];
  __shared__ int wcnt[4], wbase[4];
  int tid = threadIdx.x, lane = tid & 63, wid = tid >> 6;
  const int SPAN = NP / 4;                     // 2016
  int start = wid * SPAN, end = start + SPAN;

  int cnt = 0;
  for (int t = 0; t < 32; ++t) {               // 2016 = 31.5*64 -> guard
    int p = start + t*64 + lane;
    bool v = false; float r = 0.f, c = 0.f;
    if (p < end) v = cand_point(src, p, r, c);
    unsigned long long m = __ballot(v ? 1 : 0);
    if (v) cval[p] = make_float2(r, c);
    if (lane == 0) cmask[wid*32 + t] = m;
    cnt += __popcll(m);
  }
  if (lane == 0) wcnt[wid] = cnt;
  __syncthreads();
  if (tid == 0) {
    int run = 0;
    for (int w = 0; w < 4; ++w) { wbase[w] = run; run += wcnt[w]; }
    cnt_out[b] = run;
    if (!which) { acc[b] = 0.f; acc[4 + b] = 0.f; if (b == 0) *ctr = 0; }
  }
  __syncthreads();
  int off = wbase[wid];
  for (int t = 0; t < 32; ++t) {
    unsigned long long m = cmask[wid*32 + t];
    int p = start + t*64 + lane;
    if ((m >> lane) & 1ull)
      dst[off + __popcll(m & ((1ull << lane) - 1ull))] = cval[p];
    off += __popcll(m);
  }

  if (which) {  // L1 partial for batch b
    const float* pr = pred + b*HH*WW;
    const float* g  = gt   + b*HH*WW;
    float loc = 0.f;
    for (int p = tid; p < HH*WW; p += 256) loc += fabsf(pr[p] - g[p]);
    for (int o = 32; o; o >>= 1) loc += __shfl_down(loc, o);
    __shared__ float ws4[4];
    if (lane == 0) ws4[wid] = loc;
    __syncthreads();
    if (tid == 0) acc[8 + b] = ws4[0] + ws4[1] + ws4[2] + ws4[3];
  }
}

// K2: G in LDS (40.7 KB -> 4 blocks/CU); 8-way lane split x 4 ILP chains
// per lane (2x ds_read_b128 / iter, sentinel-padded, branch-free);
// lexicographic (d2,j) merge = first-index argmin; fused finalize via
// completion counter.
__global__ __launch_bounds__(256) void k_nn(const float* __restrict__ pred,
                                            const float2* __restrict__ Pp,
                                            const float2* __restrict__ Gp,
                                            const int* __restrict__ NPv,
                                            const int* __restrict__ NGv,
                                            float* __restrict__ acc,
                                            int* __restrict__ ctr,
                                            float* __restrict__ out) {
  __shared__ __align__(16) float2 Gs[NGCAP];   // 40704 B
  __shared__ int lastFlag;

  int bb = blockIdx.x;
  int b = bb / NBLK_P;
  int chunk = bb - b * NBLK_P;
  int npv = NPv[b], ng = NGv[b];
  int pbase = chunk * PPB;
  int tid = threadIdx.x;
  bool hasWork = (pbase < npv);

  int ngs = min(ng, NGCAP);
  int ngp = (ngs + 31) & ~31;                  // sentinel-padded count
  const float2* Gb = Gp + (size_t)b * NP;

  if (hasWork) {
    for (int i = tid; i < ngs; i += 256) Gs[i] = Gb[i];
    for (int i = ngs + tid; i < ngp; i += 256) Gs[i] = make_float2(SENTV, SENTV);
  }
  __syncthreads();

  int s = tid & 7, grp = tid >> 3;
  int pIdx = pbase + grp;
  const float* sp = pred + b*HH*WW;
  float contribS = 0.f, contribN = 0.f;

  if (hasWork && pIdx < npv) {
    float2 P = Pp[(size_t)b * NP + pIdx];
    float prr = P.x, pcc = P.y;
    float p2 = prr*prr + pcc*pcc;

    float d0 = BIGF, d1 = BIGF, d2c = BIGF, d3 = BIGF;
    int   j0 = 0x7fffffff, j1 = 0x7fffffff, j2 = 0x7fffffff, j3 = 0x7fffffff;
    const float4* G4 = (const float4*)Gs;
    int nk = ngp >> 5;
    #pragma unroll 2
    for (int k = 0; k < nk; ++k) {
      int fb = (k << 4) + (s << 1);            // float4 index
      float4 ga = G4[fb];
      float4 gb = G4[fb + 1];
      int jb = (k << 5) + (s << 2);
      float t, dd;
      dd = fmaf(ga.x, ga.x, p2); dd = fmaf(ga.y, ga.y, dd);
      t  = ga.x * prr;           t  = fmaf(ga.y, pcc, t);
      dd = fmaf(-2.f, t, dd);
      if (dd < d0) { d0 = dd; j0 = jb; }
      dd = fmaf(ga.z, ga.z, p2); dd = fmaf(ga.w, ga.w, dd);
      t  = ga.z * prr;           t  = fmaf(ga.w, pcc, t);
      dd = fmaf(-2.f, t, dd);
      if (dd < d1) { d1 = dd; j1 = jb + 1; }
      dd = fmaf(gb.x, gb.x, p2); dd = fmaf(gb.y, gb.y, dd);
      t  = gb.x * prr;           t  = fmaf(gb.y, pcc, t);
      dd = fmaf(-2.f, t, dd);
      if (dd < d2c) { d2c = dd; j2 = jb + 2; }
      dd = fmaf(gb.z, gb.z, p2); dd = fmaf(gb.w, gb.w, dd);
      t  = gb.z * prr;           t  = fmaf(gb.w, pcc, t);
      dd = fmaf(-2.f, t, dd);
      if (dd < d3) { d3 = dd; j3 = jb + 3; }
    }
    // global tail (only if ng > NGCAP; never on this data)
    for (int j = NGCAP + s; j < ng; j += 8) {
      float2 g = Gb[j];
      float t, dd;
      dd = fmaf(g.x, g.x, p2); dd = fmaf(g.y, g.y, dd);
      t  = g.x * prr;          t  = fmaf(g.y, pcc, t);
      dd = fmaf(-2.f, t, dd);
      if (dd < d0) { d0 = dd; j0 = j; }
    }
    // merge 4 chains, lexicographic (d2, j) = first-index tie-break
    float bd = d0; int bj = j0;
    if (d1 < bd || (d1 == bd && j1 < bj)) { bd = d1; bj = j1; }
    if (d2c < bd || (d2c == bd && j2 < bj)) { bd = d2c; bj = j2; }
    if (d3 < bd || (d3 == bd && j3 < bj)) { bd = d3; bj = j3; }
    // 8-lane butterfly
    for (int moff = 1; moff <= 4; moff <<= 1) {
      float od = __shfl_xor(bd, moff);
      int   oj = __shfl_xor(bj, moff);
      if (od < bd || (od == bd && oj < bj)) { bd = od; bj = oj; }
    }
    if (s == 0) {
      float minP = sqrtf(fmaxf(bd, 0.f));
      if (minP <= BANDF) {
        int sj = (bj >= 0 && bj < ngs) ? bj : 0;
        float2 gbest = (bj < ngs) ? Gs[sj] : Gb[min(bj, ng-1)];
        int r0 = min(max((int)floorf(prr), 0), HH-1);
        int c0 = min(max((int)floorf(pcc), 0), WW-1);
        int r1 = min(r0 + 1, HH-1), c1 = min(c0 + 1, WW-1);
        float dr = prr - (float)r0, dc = pcc - (float)c0;
        float w00 = (1.f-dr)*(1.f-dc), w01 = (1.f-dr)*dc;
        float w10 = dr*(1.f-dc),       w11 = dr*dc;
        float nar, nac, nbr, nbc, ncr, ncc, ndr, ndc;
        normal_at(sp, r0, c0, nar, nac);
        normal_at(sp, r0, c1, nbr, nbc);
        normal_at(sp, r1, c0, ncr, ncc);
        normal_at(sp, r1, c1, ndr, ndc);
        float nr  = w00*nar + w01*nbr + w10*ncr + w11*ndr;
        float nc2 = w00*nac + w01*nbc + w10*ncc + w11*ndc;
        float bilin = w00*sp[r0*WW+c0] + w01*sp[r0*WW+c1]
                    + w10*sp[r1*WW+c0] + w11*sp[r1*WW+c1];
        float dlr = gbest.x - prr, dlc = gbest.y - pcc;   // G[idx] - P
        contribN = fabsf(nr) + fabsf(nc2);
        contribS = (dlr*nr + dlc*nc2) * bilin;
      }
    }
  }

  // wave sum (nonzero only at s==0 lanes), one atomic per wave
  for (int o = 8; o < 64; o <<= 1) {
    contribS += __shfl_xor(contribS, o);
    contribN += __shfl_xor(contribN, o);
  }
  if ((tid & 63) == 0 && (contribS != 0.f || contribN != 0.f)) {
    atomicAdd(&acc[b],     contribS);
    atomicAdd(&acc[4 + b], contribN);
  }

  // fused finalize: last block computes the scalar
  __threadfence();
  if (tid == 0) {
    int old = atomicAdd(ctr, 1);
    lastFlag = (old == GRID_NN - 1) ? 1 : 0;
  }
  __syncthreads();
  if (lastFlag && tid == 0) {
    float ps = 0.f, l1 = 0.f;
    for (int bi = 0; bi < NB; ++bi) {
      float S = atomicAdd(&acc[bi], 0.f);       // coherent read
      float N = atomicAdd(&acc[4 + bi], 0.f);
      ps += -(S / (N + 1e-8f));                 // pseudo_b (SCALE=1, NORM_N)
      l1 += acc[8 + bi];                        // written by k_prep (prev kernel)
    }
    out[0] = ps * (1.0f / NB) + l1 * (1.0f / (NB * HH * WW));
  }
}

extern "C" void kernel_launch(void* const* d_in, const int* in_sizes, int n_in,
                              void* d_out, int out_size, void* d_ws, size_t ws_size,
                              hipStream_t stream) {
  const float* pred = (const float*)d_in[0];
  const float* gt   = (const float*)d_in[1];
  float* out = (float*)d_out;

  float2* Pp = (float2*)d_ws;
  float2* Gp = Pp + (size_t)NB * NP;
  int*    NPv = (int*)(Gp + (size_t)NB * NP);
  int*    NGv = NPv + NB;
  float*  acc = (float*)(NGv + NB);     // 12 floats: S[4], l1n[4], l1[4]
  int*    ctr = (int*)(acc + 12);

  k_prep<<<2 * NB, 256, 0, stream>>>(pred, gt, Pp, Gp, NPv, NGv, acc, ctr);
  k_nn<<<GRID_NN, 256, 0, stream>>>(pred, Pp, Gp, NPv, NGv, acc, ctr, out);
}